// Round 5
// baseline (795.585 us; speedup 1.0000x reference)
//
#include <hip/hip_runtime.h>
#include <hip/hip_bf16.h>
#include <math.h>

#define L_SEQ  2048
#define DMODEL 1024
#define NHEAD  16
#define HEADD  64

typedef __attribute__((ext_vector_type(8))) short short8;
typedef __attribute__((ext_vector_type(4))) short short4v;
typedef __attribute__((ext_vector_type(4))) float f32x4;

#define LDA 32   // unpadded: global_load_lds writes lane*16B contiguous

// RNE float -> bf16 bits
static __device__ __forceinline__ unsigned short f2bf(float f) {
    unsigned int u = __float_as_uint(f);
    unsigned int r = (u + 0x7fffu + ((u >> 16) & 1u)) >> 16;
    return (unsigned short)r;
}

static __device__ __forceinline__ void dma16(const unsigned short* g, unsigned short* l) {
    __builtin_amdgcn_global_load_lds((const __attribute__((address_space(1))) void*)g,
                                     (__attribute__((address_space(3))) void*)l, 16, 0, 0);
}

__global__ void cvt_f32_bf16(const float* __restrict__ in,
                             unsigned short* __restrict__ out, int n4) {
    int i = blockIdx.x * blockDim.x + threadIdx.x;
    if (i >= n4) return;
    float4 v = reinterpret_cast<const float4*>(in)[i];
    ushort4 o;
    o.x = f2bf(v.x); o.y = f2bf(v.y); o.z = f2bf(v.z); o.w = f2bf(v.w);
    reinterpret_cast<ushort4*>(out)[i] = o;
}

// ---------------- projection GEMM: C[m][n] = sum_k X[m][k]*W[n][k] + b[n] ----
// mode 0: Q (RoPE + scale log2e/8), mode 1: K (RoPE) -> [bh][l][d]
// mode 2: V (plain)                                  -> [bh][d][l] (transposed)
__global__ __launch_bounds__(256) void proj_gemm(
    const unsigned short* __restrict__ X,
    const unsigned short* __restrict__ W,
    const float* __restrict__ bias,
    unsigned short* __restrict__ out,
    int mode)
{
    __shared__ unsigned short a_lds[128 * LDA];
    __shared__ unsigned short b_lds[128 * LDA];
    const int tid  = threadIdx.x;
    const int lane = tid & 63;
    const int w    = tid >> 6;
    const int wm   = w & 1, wn = w >> 1;
    const int quad = lane >> 4, l16 = lane & 15;
    const int m0 = blockIdx.y * 128;
    const int n0 = blockIdx.x * 128;

    f32x4 acc[4][4];
#pragma unroll
    for (int i = 0; i < 4; ++i)
#pragma unroll
        for (int j = 0; j < 4; ++j) acc[i][j] = (f32x4){0.f, 0.f, 0.f, 0.f};

    const int drow = lane >> 2;            // 0..15
    const int dcol = (lane & 3) << 3;      // shorts (lane&3 * 16B)

    for (int kk = 0; kk < DMODEL; kk += 32) {
        __syncthreads();                   // prior iter's readers done
        // wave w stages rows 32w..32w+31 of A and B (2 DMA instrs each)
#pragma unroll
        for (int t = 0; t < 2; ++t) {
            int r0 = w * 32 + t * 16;
            dma16(X + (size_t)(m0 + r0 + drow) * DMODEL + kk + dcol, &a_lds[r0 * LDA]);
            dma16(W + (size_t)(n0 + r0 + drow) * DMODEL + kk + dcol, &b_lds[r0 * LDA]);
        }
        __syncthreads();                   // drains vmcnt before barrier
        short8 af[4], bf[4];
#pragma unroll
        for (int mt = 0; mt < 4; ++mt)
            af[mt] = *reinterpret_cast<const short8*>(&a_lds[(wm * 64 + mt * 16 + l16) * LDA + quad * 8]);
#pragma unroll
        for (int nt = 0; nt < 4; ++nt)
            bf[nt] = *reinterpret_cast<const short8*>(&b_lds[(wn * 64 + nt * 16 + l16) * LDA + quad * 8]);
#pragma unroll
        for (int mt = 0; mt < 4; ++mt)
#pragma unroll
            for (int nt = 0; nt < 4; ++nt)
                acc[mt][nt] = __builtin_amdgcn_mfma_f32_16x16x32_bf16(af[mt], bf[nt], acc[mt][nt], 0, 0, 0);
    }

    // epilogue: bias (+ RoPE for Q/K); V stored transposed
#pragma unroll
    for (int nt = 0; nt < 4; ++nt) {
        int n_g = n0 + wn * 64 + nt * 16 + l16;
        float bv = bias[n_g];
        int d  = n_g & (HEADD - 1);
        int h  = n_g >> 6;
        float sgn = (d & 1) ? 1.0f : -1.0f;
        int i2 = d >> 1;
        float inv_f = expf(-0.28782313662425574f * (float)i2);  // 10000^(-i2/32)
#pragma unroll
        for (int mt = 0; mt < 4; ++mt) {
#pragma unroll
            for (int r = 0; r < 4; ++r) {
                int m_g = m0 + wm * 64 + mt * 16 + quad * 4 + r;
                float v = acc[mt][nt][r] + bv;
                int b    = m_g >> 11;
                int lpos = m_g & (L_SEQ - 1);
                if (mode < 2) {
                    float p = __shfl_xor(v, 1);   // partner (d^1), same row
                    float ang = (float)lpos * inv_f;
                    float cv = cosf(ang), sv = sinf(ang);
                    v = v * cv + sgn * sv * p;
                    // fold 1/sqrt(HD) * log2(e) into Q: attn uses exp2
                    if (mode == 0) v *= 0.18033688011112042f;
                    out[((size_t)(b * NHEAD + h) * L_SEQ + lpos) * HEADD + d] = f2bf(v);
                } else {
                    out[((size_t)(b * NHEAD + h) * HEADD + d) * L_SEQ + lpos] = f2bf(v);
                }
            }
        }
    }
}

// ---------------- flash attention (causal), S^T formulation -----------------
// grid (16, B*H); block `pair` does q-tiles {pair, 31-pair} (33 iters each).
// S^T = K*Q^T: its C-layout (lane: qrow=l16, seqcol=quad*4+r) IS the A-frag
// layout of mfma_16x16x16 (lane: m=l16, k=quad*4+j), so P=exp2(S^T) feeds PV
// directly from registers -- no LDS round-trip, no shuffles in the loop.
#define LDK 88   // row stride 44 dw: frag-read start banks spread mod 32

__global__ __launch_bounds__(256) void attn_fwd(
    const unsigned short* __restrict__ Q,
    const unsigned short* __restrict__ K,
    const unsigned short* __restrict__ Vt,
    unsigned short* __restrict__ Oa)
{
    __shared__ unsigned short k_lds[64 * LDK];
    __shared__ unsigned short v_lds[64 * LDK];
    const int tid  = threadIdx.x;
    const int lane = tid & 63;
    const int w    = tid >> 6;
    const int quad = lane >> 4, l16 = lane & 15;
    const int pair = blockIdx.x;
    const int bh   = blockIdx.y;
    const size_t base = (size_t)bh * L_SEQ * HEADD;

    const int srow0 = tid >> 3;
    const int scc   = (tid & 7) << 3;
    const int b = bh >> 4, h = bh & 15;

    for (int half = 0; half < 2; ++half) {
        const int qb = half ? (31 - pair) : pair;
        const int qrow = qb * 64 + w * 16 + l16;

        short8 qf[2];
#pragma unroll
        for (int ks = 0; ks < 2; ++ks)
            qf[ks] = *reinterpret_cast<const short8*>(Q + base + (size_t)qrow * HEADD + ks * 32 + quad * 8);

        f32x4 o[4];
#pragma unroll
        for (int nt = 0; nt < 4; ++nt) o[nt] = (f32x4){0.f, 0.f, 0.f, 0.f};
        float lsum = 0.f;   // per-lane partial sum, all for q-row l16

        int4 ka0 = *reinterpret_cast<const int4*>(K  + base + (size_t)srow0 * HEADD + scc);
        int4 ka1 = *reinterpret_cast<const int4*>(K  + base + (size_t)(srow0 + 32) * HEADD + scc);
        int4 va0 = *reinterpret_cast<const int4*>(Vt + base + (size_t)srow0 * L_SEQ + scc);
        int4 va1 = *reinterpret_cast<const int4*>(Vt + base + (size_t)(srow0 + 32) * L_SEQ + scc);

        for (int kb = 0; kb <= qb; ++kb) {
            __syncthreads();
            *reinterpret_cast<int4*>(&k_lds[srow0 * LDK + scc])        = ka0;
            *reinterpret_cast<int4*>(&k_lds[(srow0 + 32) * LDK + scc]) = ka1;
            *reinterpret_cast<int4*>(&v_lds[srow0 * LDK + scc])        = va0;
            *reinterpret_cast<int4*>(&v_lds[(srow0 + 32) * LDK + scc]) = va1;
            __syncthreads();

            if (kb < qb) {   // prefetch next tile; lands during compute
                int kn = kb + 1;
                ka0 = *reinterpret_cast<const int4*>(K  + base + (size_t)(kn * 64 + srow0) * HEADD + scc);
                ka1 = *reinterpret_cast<const int4*>(K  + base + (size_t)(kn * 64 + srow0 + 32) * HEADD + scc);
                va0 = *reinterpret_cast<const int4*>(Vt + base + (size_t)srow0 * L_SEQ + kn * 64 + scc);
                va1 = *reinterpret_cast<const int4*>(Vt + base + (size_t)(srow0 + 32) * L_SEQ + kn * 64 + scc);
            }

            // S^T[seqcol][qrow]: A = K-frag (m=seqcol), B = Q-frag (n=qrow)
            f32x4 st[4];
#pragma unroll
            for (int nt = 0; nt < 4; ++nt) st[nt] = (f32x4){0.f, 0.f, 0.f, 0.f};
#pragma unroll
            for (int ks = 0; ks < 2; ++ks)
#pragma unroll
                for (int nt = 0; nt < 4; ++nt) {
                    short8 kf = *reinterpret_cast<const short8*>(&k_lds[(nt * 16 + l16) * LDK + ks * 32 + quad * 8]);
                    st[nt] = __builtin_amdgcn_mfma_f32_16x16x32_bf16(kf, qf[ks], st[nt], 0, 0, 0);
                }

            if (kb == qb) {   // causal: seqcol > qrow -> -inf (exp2 -> 0)
#pragma unroll
                for (int nt = 0; nt < 4; ++nt)
#pragma unroll
                    for (int r = 0; r < 4; ++r) {
                        int seqcol = kb * 64 + nt * 16 + quad * 4 + r;
                        if (seqcol > qrow) st[nt][r] = -INFINITY;
                    }
            }

            // p = exp2(s); pack 4 bf16 (round-half-up) = PV A-frag; sum lsum
            short4v pfrag[4];
#pragma unroll
            for (int nt = 0; nt < 4; ++nt) {
                float p0 = __builtin_amdgcn_exp2f(st[nt][0]);
                float p1 = __builtin_amdgcn_exp2f(st[nt][1]);
                float p2 = __builtin_amdgcn_exp2f(st[nt][2]);
                float p3 = __builtin_amdgcn_exp2f(st[nt][3]);
                lsum += (p0 + p1) + (p2 + p3);
                unsigned u0 = __float_as_uint(p0) + 0x8000u;
                unsigned u1 = __float_as_uint(p1) + 0x8000u;
                unsigned u2 = __float_as_uint(p2) + 0x8000u;
                unsigned u3 = __float_as_uint(p3) + 0x8000u;
                union { unsigned u[2]; short4v v; } pk;
                pk.u[0] = (u0 >> 16) | (u1 & 0xffff0000u);
                pk.u[1] = (u2 >> 16) | (u3 & 0xffff0000u);
                pfrag[nt] = pk.v;
            }

            // O += P * V ; B-frag: lane(q,l16): V[k=16c+4q+j][d=nt2*16+l16]
#pragma unroll
            for (int c = 0; c < 4; ++c)
#pragma unroll
                for (int nt2 = 0; nt2 < 4; ++nt2) {
                    short4v vf = *reinterpret_cast<const short4v*>(
                        &v_lds[(nt2 * 16 + l16) * LDK + c * 16 + quad * 4]);
                    o[nt2] = __builtin_amdgcn_mfma_f32_16x16x16bf16_1k(pfrag[c], vf, o[nt2], 0, 0, 0);
                }
        }

        // reduce q-row sums across quads (row = l16), broadcast to reg rows
        lsum += __shfl_xor(lsum, 16);
        lsum += __shfl_xor(lsum, 32);
        float rs[4];
#pragma unroll
        for (int r = 0; r < 4; ++r) rs[r] = __shfl(lsum, quad * 4 + r);
#pragma unroll
        for (int r = 0; r < 4; ++r) {
            float inv = 1.0f / rs[r];
            int lg = qb * 64 + w * 16 + quad * 4 + r;
#pragma unroll
            for (int nt = 0; nt < 4; ++nt) {
                int d = nt * 16 + l16;
                Oa[(size_t)(b * L_SEQ + lg) * DMODEL + h * HEADD + d] = f2bf(o[nt][r] * inv);
            }
        }
    }
}

// ---------------- output projection: fp32 out = A @ Wo^T + bo ---------------
__global__ __launch_bounds__(256) void out_gemm(
    const unsigned short* __restrict__ X,
    const unsigned short* __restrict__ W,
    const float* __restrict__ bias,
    float* __restrict__ out)
{
    __shared__ unsigned short a_lds[128 * LDA];
    __shared__ unsigned short b_lds[128 * LDA];
    const int tid  = threadIdx.x;
    const int lane = tid & 63;
    const int w    = tid >> 6;
    const int wm   = w & 1, wn = w >> 1;
    const int quad = lane >> 4, l16 = lane & 15;
    const int m0 = blockIdx.y * 128;
    const int n0 = blockIdx.x * 128;

    f32x4 acc[4][4];
#pragma unroll
    for (int i = 0; i < 4; ++i)
#pragma unroll
        for (int j = 0; j < 4; ++j) acc[i][j] = (f32x4){0.f, 0.f, 0.f, 0.f};

    const int drow = lane >> 2;
    const int dcol = (lane & 3) << 3;

    for (int kk = 0; kk < DMODEL; kk += 32) {
        __syncthreads();
#pragma unroll
        for (int t = 0; t < 2; ++t) {
            int r0 = w * 32 + t * 16;
            dma16(X + (size_t)(m0 + r0 + drow) * DMODEL + kk + dcol, &a_lds[r0 * LDA]);
            dma16(W + (size_t)(n0 + r0 + drow) * DMODEL + kk + dcol, &b_lds[r0 * LDA]);
        }
        __syncthreads();
        short8 af[4], bf[4];
#pragma unroll
        for (int mt = 0; mt < 4; ++mt)
            af[mt] = *reinterpret_cast<const short8*>(&a_lds[(wm * 64 + mt * 16 + l16) * LDA + quad * 8]);
#pragma unroll
        for (int nt = 0; nt < 4; ++nt)
            bf[nt] = *reinterpret_cast<const short8*>(&b_lds[(wn * 64 + nt * 16 + l16) * LDA + quad * 8]);
#pragma unroll
        for (int mt = 0; mt < 4; ++mt)
#pragma unroll
            for (int nt = 0; nt < 4; ++nt)
                acc[mt][nt] = __builtin_amdgcn_mfma_f32_16x16x32_bf16(af[mt], bf[nt], acc[mt][nt], 0, 0, 0);
    }

#pragma unroll
    for (int nt = 0; nt < 4; ++nt) {
        int n_g = n0 + wn * 64 + nt * 16 + l16;
        float bv = bias[n_g];
#pragma unroll
        for (int mt = 0; mt < 4; ++mt)
#pragma unroll
            for (int r = 0; r < 4; ++r) {
                int m_g = m0 + wm * 64 + mt * 16 + quad * 4 + r;
                out[(size_t)m_g * DMODEL + n_g] = acc[mt][nt][r] + bv;
            }
    }
}

extern "C" void kernel_launch(void* const* d_in, const int* in_sizes, int n_in,
                              void* d_out, int out_size, void* d_ws, size_t ws_size,
                              hipStream_t stream) {
    const float* query = (const float*)d_in[0];
    const float* Wq = (const float*)d_in[1];
    const float* bq = (const float*)d_in[2];
    const float* Wk = (const float*)d_in[3];
    const float* bk = (const float*)d_in[4];
    const float* Wv = (const float*)d_in[5];
    const float* bv = (const float*)d_in[6];
    const float* Wo = (const float*)d_in[7];
    const float* bo = (const float*)d_in[8];
    float* out = (float*)d_out;

    unsigned short* ws  = (unsigned short*)d_ws;
    unsigned short* xb  = ws;                       // 8192*1024
    unsigned short* wqb = xb  + (size_t)8388608;    // 1024*1024 each
    unsigned short* wkb = wqb + 1048576;
    unsigned short* wvb = wkb + 1048576;
    unsigned short* wob = wvb + 1048576;
    unsigned short* Qb  = wob + 1048576;            // [bh][l][d]
    unsigned short* Kb  = Qb  + 8388608;
    unsigned short* Vtb = Kb  + 8388608;            // [bh][d][l]
    unsigned short* Ab  = Vtb + 8388608;            // [b][l][h*d]

    cvt_f32_bf16<<<8192, 256, 0, stream>>>(query, xb, 2097152);
    cvt_f32_bf16<<<1024, 256, 0, stream>>>(Wq, wqb, 262144);
    cvt_f32_bf16<<<1024, 256, 0, stream>>>(Wk, wkb, 262144);
    cvt_f32_bf16<<<1024, 256, 0, stream>>>(Wv, wvb, 262144);
    cvt_f32_bf16<<<1024, 256, 0, stream>>>(Wo, wob, 262144);

    dim3 pg(8, 64);
    proj_gemm<<<pg, 256, 0, stream>>>(xb, wqb, bq, Qb, 0);
    proj_gemm<<<pg, 256, 0, stream>>>(xb, wkb, bk, Kb, 1);
    proj_gemm<<<pg, 256, 0, stream>>>(xb, wvb, bv, Vtb, 2);
    attn_fwd<<<dim3(16, 64), 256, 0, stream>>>(Qb, Kb, Vtb, Ab);
    out_gemm<<<pg, 256, 0, stream>>>(Ab, wob, bo, out);
}

// Round 6
// 399.436 us; speedup vs baseline: 1.9918x; 1.9918x over previous
//
#include <hip/hip_runtime.h>
#include <hip/hip_bf16.h>
#include <math.h>

#define L_SEQ  2048
#define DMODEL 1024
#define NHEAD  16
#define HEADD  64

typedef __attribute__((ext_vector_type(8))) short short8;
typedef __attribute__((ext_vector_type(4))) short short4v;
typedef __attribute__((ext_vector_type(4))) float f32x4;

#define LDA 32   // unpadded: global_load_lds writes lane*16B contiguous

// RNE float -> bf16 bits
static __device__ __forceinline__ unsigned short f2bf(float f) {
    unsigned int u = __float_as_uint(f);
    unsigned int r = (u + 0x7fffu + ((u >> 16) & 1u)) >> 16;
    return (unsigned short)r;
}

static __device__ __forceinline__ void dma16(const unsigned short* g, unsigned short* l) {
    __builtin_amdgcn_global_load_lds((const __attribute__((address_space(1))) void*)g,
                                     (__attribute__((address_space(3))) void*)l, 16, 0, 0);
}

__global__ void cvt_f32_bf16(const float* __restrict__ in,
                             unsigned short* __restrict__ out, int n4) {
    int i = blockIdx.x * blockDim.x + threadIdx.x;
    if (i >= n4) return;
    float4 v = reinterpret_cast<const float4*>(in)[i];
    ushort4 o;
    o.x = f2bf(v.x); o.y = f2bf(v.y); o.z = f2bf(v.z); o.w = f2bf(v.w);
    reinterpret_cast<ushort4*>(out)[i] = o;
}

// ---------------- projection GEMM: C[m][n] = sum_k X[m][k]*W[n][k] + b[n] ----
// mode 0: Q (RoPE + scale log2e/8), mode 1: K (RoPE), mode 2: V (plain)
// output layout [b*NHEAD+h][l][d] bf16 (DENSE store; V transposed separately —
// a [bh][d][l] epilogue store is 2B/4KB-stride scatter -> ~116B HBM write per
// 2B store, measured 976 MB WRITE_SIZE in round 5)
__global__ __launch_bounds__(256) void proj_gemm(
    const unsigned short* __restrict__ X,
    const unsigned short* __restrict__ W,
    const float* __restrict__ bias,
    unsigned short* __restrict__ out,
    int mode)
{
    __shared__ unsigned short a_lds[128 * LDA];
    __shared__ unsigned short b_lds[128 * LDA];
    const int tid  = threadIdx.x;
    const int lane = tid & 63;
    const int w    = tid >> 6;
    const int wm   = w & 1, wn = w >> 1;
    const int quad = lane >> 4, l16 = lane & 15;
    const int m0 = blockIdx.y * 128;
    const int n0 = blockIdx.x * 128;

    f32x4 acc[4][4];
#pragma unroll
    for (int i = 0; i < 4; ++i)
#pragma unroll
        for (int j = 0; j < 4; ++j) acc[i][j] = (f32x4){0.f, 0.f, 0.f, 0.f};

    const int drow = lane >> 2;            // 0..15
    const int dcol = (lane & 3) << 3;      // shorts (lane&3 * 16B)

    for (int kk = 0; kk < DMODEL; kk += 32) {
        __syncthreads();                   // prior iter's readers done
#pragma unroll
        for (int t = 0; t < 2; ++t) {
            int r0 = w * 32 + t * 16;
            dma16(X + (size_t)(m0 + r0 + drow) * DMODEL + kk + dcol, &a_lds[r0 * LDA]);
            dma16(W + (size_t)(n0 + r0 + drow) * DMODEL + kk + dcol, &b_lds[r0 * LDA]);
        }
        __syncthreads();                   // drains vmcnt before barrier
        short8 af[4], bf[4];
#pragma unroll
        for (int mt = 0; mt < 4; ++mt)
            af[mt] = *reinterpret_cast<const short8*>(&a_lds[(wm * 64 + mt * 16 + l16) * LDA + quad * 8]);
#pragma unroll
        for (int nt = 0; nt < 4; ++nt)
            bf[nt] = *reinterpret_cast<const short8*>(&b_lds[(wn * 64 + nt * 16 + l16) * LDA + quad * 8]);
#pragma unroll
        for (int mt = 0; mt < 4; ++mt)
#pragma unroll
            for (int nt = 0; nt < 4; ++nt)
                acc[mt][nt] = __builtin_amdgcn_mfma_f32_16x16x32_bf16(af[mt], bf[nt], acc[mt][nt], 0, 0, 0);
    }

    // epilogue: bias (+ RoPE for Q/K); all modes store dense [bh][l][d]
#pragma unroll
    for (int nt = 0; nt < 4; ++nt) {
        int n_g = n0 + wn * 64 + nt * 16 + l16;
        float bv = bias[n_g];
        int d  = n_g & (HEADD - 1);
        int h  = n_g >> 6;
        float sgn = (d & 1) ? 1.0f : -1.0f;
        int i2 = d >> 1;
        float inv_f = expf(-0.28782313662425574f * (float)i2);  // 10000^(-i2/32)
#pragma unroll
        for (int mt = 0; mt < 4; ++mt) {
#pragma unroll
            for (int r = 0; r < 4; ++r) {
                int m_g = m0 + wm * 64 + mt * 16 + quad * 4 + r;
                float v = acc[mt][nt][r] + bv;
                int b    = m_g >> 11;
                int lpos = m_g & (L_SEQ - 1);
                if (mode < 2) {
                    float p = __shfl_xor(v, 1);   // partner (d^1), same row
                    float ang = (float)lpos * inv_f;
                    float cv = cosf(ang), sv = sinf(ang);
                    v = v * cv + sgn * sv * p;
                    // fold 1/sqrt(HD) * log2(e) into Q: attn uses exp2
                    if (mode == 0) v *= 0.18033688011112042f;
                }
                out[((size_t)(b * NHEAD + h) * L_SEQ + lpos) * HEADD + d] = f2bf(v);
            }
        }
    }
}

// ---------------- V transpose: [bh][l][d] -> [bh][d][l] ---------------------
__global__ __launch_bounds__(256) void transpose_v(
    const unsigned short* __restrict__ Vr, unsigned short* __restrict__ Vt)
{
    __shared__ unsigned short tile[64 * 72];
    const int tid = threadIdx.x;
    const int bh  = blockIdx.y;
    const int l0  = blockIdx.x * 64;
#pragma unroll
    for (int t = 0; t < 2; ++t) {
        int c = tid + t * 256;
        int row = c >> 3, cc = (c & 7) << 3;
        int4 v = *reinterpret_cast<const int4*>(Vr + ((size_t)bh * L_SEQ + l0 + row) * HEADD + cc);
        *reinterpret_cast<int4*>(&tile[row * 72 + cc]) = v;
    }
    __syncthreads();
#pragma unroll
    for (int t = 0; t < 2; ++t) {
        int c = tid + t * 256;
        int d = c >> 3, lc = (c & 7) << 3;
        union { unsigned short u[8]; int4 v; } tt;
#pragma unroll
        for (int j = 0; j < 8; ++j) tt.u[j] = tile[(lc + j) * 72 + d];
        *reinterpret_cast<int4*>(Vt + ((size_t)bh * HEADD + d) * L_SEQ + l0 + lc) = tt.v;
    }
}

// ---------------- flash attention (causal), S^T formulation -----------------
// grid (16, B*H); block `pair` does q-tiles {pair, 31-pair} (33 iters each).
// S^T = K*Q^T: its C-layout (lane: qrow=l16, seqcol=quad*4+r) IS the A-frag
// layout of mfma_16x16x16 (lane: m=l16, k=quad*4+j), so P=exp2(S^T) feeds PV
// directly from registers -- no LDS round-trip, no shuffles in the loop.
#define LDK 88   // row stride 44 dw: frag-read start banks spread mod 32

__global__ __launch_bounds__(256) void attn_fwd(
    const unsigned short* __restrict__ Q,
    const unsigned short* __restrict__ K,
    const unsigned short* __restrict__ Vt,
    unsigned short* __restrict__ Oa)
{
    __shared__ unsigned short k_lds[64 * LDK];
    __shared__ unsigned short v_lds[64 * LDK];
    const int tid  = threadIdx.x;
    const int lane = tid & 63;
    const int w    = tid >> 6;
    const int quad = lane >> 4, l16 = lane & 15;
    const int pair = blockIdx.x;
    const int bh   = blockIdx.y;
    const size_t base = (size_t)bh * L_SEQ * HEADD;

    const int srow0 = tid >> 3;
    const int scc   = (tid & 7) << 3;
    const int b = bh >> 4, h = bh & 15;

    for (int half = 0; half < 2; ++half) {
        const int qb = half ? (31 - pair) : pair;
        const int qrow = qb * 64 + w * 16 + l16;

        short8 qf[2];
#pragma unroll
        for (int ks = 0; ks < 2; ++ks)
            qf[ks] = *reinterpret_cast<const short8*>(Q + base + (size_t)qrow * HEADD + ks * 32 + quad * 8);

        f32x4 o[4];
#pragma unroll
        for (int nt = 0; nt < 4; ++nt) o[nt] = (f32x4){0.f, 0.f, 0.f, 0.f};
        float lsum = 0.f;   // per-lane partial sum, all for q-row l16

        int4 ka0 = *reinterpret_cast<const int4*>(K  + base + (size_t)srow0 * HEADD + scc);
        int4 ka1 = *reinterpret_cast<const int4*>(K  + base + (size_t)(srow0 + 32) * HEADD + scc);
        int4 va0 = *reinterpret_cast<const int4*>(Vt + base + (size_t)srow0 * L_SEQ + scc);
        int4 va1 = *reinterpret_cast<const int4*>(Vt + base + (size_t)(srow0 + 32) * L_SEQ + scc);

        for (int kb = 0; kb <= qb; ++kb) {
            __syncthreads();
            *reinterpret_cast<int4*>(&k_lds[srow0 * LDK + scc])        = ka0;
            *reinterpret_cast<int4*>(&k_lds[(srow0 + 32) * LDK + scc]) = ka1;
            *reinterpret_cast<int4*>(&v_lds[srow0 * LDK + scc])        = va0;
            *reinterpret_cast<int4*>(&v_lds[(srow0 + 32) * LDK + scc]) = va1;
            __syncthreads();

            if (kb < qb) {   // prefetch next tile; lands during compute
                int kn = kb + 1;
                ka0 = *reinterpret_cast<const int4*>(K  + base + (size_t)(kn * 64 + srow0) * HEADD + scc);
                ka1 = *reinterpret_cast<const int4*>(K  + base + (size_t)(kn * 64 + srow0 + 32) * HEADD + scc);
                va0 = *reinterpret_cast<const int4*>(Vt + base + (size_t)srow0 * L_SEQ + kn * 64 + scc);
                va1 = *reinterpret_cast<const int4*>(Vt + base + (size_t)(srow0 + 32) * L_SEQ + kn * 64 + scc);
            }

            // S^T[seqcol][qrow]: A = K-frag (m=seqcol), B = Q-frag (n=qrow)
            f32x4 st[4];
#pragma unroll
            for (int nt = 0; nt < 4; ++nt) st[nt] = (f32x4){0.f, 0.f, 0.f, 0.f};
#pragma unroll
            for (int ks = 0; ks < 2; ++ks)
#pragma unroll
                for (int nt = 0; nt < 4; ++nt) {
                    short8 kf = *reinterpret_cast<const short8*>(&k_lds[(nt * 16 + l16) * LDK + ks * 32 + quad * 8]);
                    st[nt] = __builtin_amdgcn_mfma_f32_16x16x32_bf16(kf, qf[ks], st[nt], 0, 0, 0);
                }

            if (kb == qb) {   // causal: seqcol > qrow -> -inf (exp2 -> 0)
#pragma unroll
                for (int nt = 0; nt < 4; ++nt)
#pragma unroll
                    for (int r = 0; r < 4; ++r) {
                        int seqcol = kb * 64 + nt * 16 + quad * 4 + r;
                        if (seqcol > qrow) st[nt][r] = -INFINITY;
                    }
            }

            // p = exp2(s); pack 4 bf16 (round-half-up) = PV A-frag; sum lsum
            short4v pfrag[4];
#pragma unroll
            for (int nt = 0; nt < 4; ++nt) {
                float p0 = __builtin_amdgcn_exp2f(st[nt][0]);
                float p1 = __builtin_amdgcn_exp2f(st[nt][1]);
                float p2 = __builtin_amdgcn_exp2f(st[nt][2]);
                float p3 = __builtin_amdgcn_exp2f(st[nt][3]);
                lsum += (p0 + p1) + (p2 + p3);
                unsigned u0 = __float_as_uint(p0) + 0x8000u;
                unsigned u1 = __float_as_uint(p1) + 0x8000u;
                unsigned u2 = __float_as_uint(p2) + 0x8000u;
                unsigned u3 = __float_as_uint(p3) + 0x8000u;
                union { unsigned u[2]; short4v v; } pk;
                pk.u[0] = (u0 >> 16) | (u1 & 0xffff0000u);
                pk.u[1] = (u2 >> 16) | (u3 & 0xffff0000u);
                pfrag[nt] = pk.v;
            }

            // O += P * V ; B-frag: lane(q,l16): V[k=16c+4q+j][d=nt2*16+l16]
#pragma unroll
            for (int c = 0; c < 4; ++c)
#pragma unroll
                for (int nt2 = 0; nt2 < 4; ++nt2) {
                    short4v vf = *reinterpret_cast<const short4v*>(
                        &v_lds[(nt2 * 16 + l16) * LDK + c * 16 + quad * 4]);
                    o[nt2] = __builtin_amdgcn_mfma_f32_16x16x16bf16_1k(pfrag[c], vf, o[nt2], 0, 0, 0);
                }
        }

        // reduce q-row sums across quads (row = l16), broadcast to reg rows
        lsum += __shfl_xor(lsum, 16);
        lsum += __shfl_xor(lsum, 32);
        float rs[4];
#pragma unroll
        for (int r = 0; r < 4; ++r) rs[r] = __shfl(lsum, quad * 4 + r);
#pragma unroll
        for (int r = 0; r < 4; ++r) {
            float inv = 1.0f / rs[r];
            int lg = qb * 64 + w * 16 + quad * 4 + r;
#pragma unroll
            for (int nt = 0; nt < 4; ++nt) {
                int d = nt * 16 + l16;
                Oa[(size_t)(b * L_SEQ + lg) * DMODEL + h * HEADD + d] = f2bf(o[nt][r] * inv);
            }
        }
    }
}

// ---------------- output projection: fp32 out = A @ Wo^T + bo ---------------
__global__ __launch_bounds__(256) void out_gemm(
    const unsigned short* __restrict__ X,
    const unsigned short* __restrict__ W,
    const float* __restrict__ bias,
    float* __restrict__ out)
{
    __shared__ unsigned short a_lds[128 * LDA];
    __shared__ unsigned short b_lds[128 * LDA];
    const int tid  = threadIdx.x;
    const int lane = tid & 63;
    const int w    = tid >> 6;
    const int wm   = w & 1, wn = w >> 1;
    const int quad = lane >> 4, l16 = lane & 15;
    const int m0 = blockIdx.y * 128;
    const int n0 = blockIdx.x * 128;

    f32x4 acc[4][4];
#pragma unroll
    for (int i = 0; i < 4; ++i)
#pragma unroll
        for (int j = 0; j < 4; ++j) acc[i][j] = (f32x4){0.f, 0.f, 0.f, 0.f};

    const int drow = lane >> 2;
    const int dcol = (lane & 3) << 3;

    for (int kk = 0; kk < DMODEL; kk += 32) {
        __syncthreads();
#pragma unroll
        for (int t = 0; t < 2; ++t) {
            int r0 = w * 32 + t * 16;
            dma16(X + (size_t)(m0 + r0 + drow) * DMODEL + kk + dcol, &a_lds[r0 * LDA]);
            dma16(W + (size_t)(n0 + r0 + drow) * DMODEL + kk + dcol, &b_lds[r0 * LDA]);
        }
        __syncthreads();
        short8 af[4], bf[4];
#pragma unroll
        for (int mt = 0; mt < 4; ++mt)
            af[mt] = *reinterpret_cast<const short8*>(&a_lds[(wm * 64 + mt * 16 + l16) * LDA + quad * 8]);
#pragma unroll
        for (int nt = 0; nt < 4; ++nt)
            bf[nt] = *reinterpret_cast<const short8*>(&b_lds[(wn * 64 + nt * 16 + l16) * LDA + quad * 8]);
#pragma unroll
        for (int mt = 0; mt < 4; ++mt)
#pragma unroll
            for (int nt = 0; nt < 4; ++nt)
                acc[mt][nt] = __builtin_amdgcn_mfma_f32_16x16x32_bf16(af[mt], bf[nt], acc[mt][nt], 0, 0, 0);
    }

#pragma unroll
    for (int nt = 0; nt < 4; ++nt) {
        int n_g = n0 + wn * 64 + nt * 16 + l16;
        float bv = bias[n_g];
#pragma unroll
        for (int mt = 0; mt < 4; ++mt)
#pragma unroll
            for (int r = 0; r < 4; ++r) {
                int m_g = m0 + wm * 64 + mt * 16 + quad * 4 + r;
                out[(size_t)m_g * DMODEL + n_g] = acc[mt][nt][r] + bv;
            }
    }
}

extern "C" void kernel_launch(void* const* d_in, const int* in_sizes, int n_in,
                              void* d_out, int out_size, void* d_ws, size_t ws_size,
                              hipStream_t stream) {
    const float* query = (const float*)d_in[0];
    const float* Wq = (const float*)d_in[1];
    const float* bq = (const float*)d_in[2];
    const float* Wk = (const float*)d_in[3];
    const float* bk = (const float*)d_in[4];
    const float* Wv = (const float*)d_in[5];
    const float* bv = (const float*)d_in[6];
    const float* Wo = (const float*)d_in[7];
    const float* bo = (const float*)d_in[8];
    float* out = (float*)d_out;

    unsigned short* ws  = (unsigned short*)d_ws;
    unsigned short* xb  = ws;                       // 8192*1024
    unsigned short* wqb = xb  + (size_t)8388608;    // 1024*1024 each
    unsigned short* wkb = wqb + 1048576;
    unsigned short* wvb = wkb + 1048576;
    unsigned short* wob = wvb + 1048576;
    unsigned short* Qb  = wob + 1048576;            // [bh][l][d]
    unsigned short* Kb  = Qb  + 8388608;
    unsigned short* Vr  = Kb  + 8388608;            // [bh][l][d]
    unsigned short* Vtb = Vr  + 8388608;            // [bh][d][l]
    unsigned short* Ab  = Vtb + 8388608;            // [b][l][h*d]

    cvt_f32_bf16<<<8192, 256, 0, stream>>>(query, xb, 2097152);
    cvt_f32_bf16<<<1024, 256, 0, stream>>>(Wq, wqb, 262144);
    cvt_f32_bf16<<<1024, 256, 0, stream>>>(Wk, wkb, 262144);
    cvt_f32_bf16<<<1024, 256, 0, stream>>>(Wv, wvb, 262144);
    cvt_f32_bf16<<<1024, 256, 0, stream>>>(Wo, wob, 262144);

    dim3 pg(8, 64);
    proj_gemm<<<pg, 256, 0, stream>>>(xb, wqb, bq, Qb, 0);
    proj_gemm<<<pg, 256, 0, stream>>>(xb, wkb, bk, Kb, 1);
    proj_gemm<<<pg, 256, 0, stream>>>(xb, wvb, bv, Vr, 2);
    transpose_v<<<dim3(32, 64), 256, 0, stream>>>(Vr, Vtb);
    attn_fwd<<<dim3(16, 64), 256, 0, stream>>>(Qb, Kb, Vtb, Ab);
    out_gemm<<<pg, 256, 0, stream>>>(Ab, wob, bo, out);
}

// Round 7
// 397.816 us; speedup vs baseline: 1.9999x; 1.0041x over previous
//
#include <hip/hip_runtime.h>
#include <hip/hip_bf16.h>
#include <math.h>

#define L_SEQ  2048
#define DMODEL 1024
#define NHEAD  16
#define HEADD  64

typedef __attribute__((ext_vector_type(8))) short short8;
typedef __attribute__((ext_vector_type(4))) short short4v;
typedef __attribute__((ext_vector_type(4))) float f32x4;

#define LDA 32   // unpadded: global_load_lds writes lane*16B contiguous

// RNE float -> bf16 bits
static __device__ __forceinline__ unsigned short f2bf(float f) {
    unsigned int u = __float_as_uint(f);
    unsigned int r = (u + 0x7fffu + ((u >> 16) & 1u)) >> 16;
    return (unsigned short)r;
}

static __device__ __forceinline__ void dma16(const unsigned short* g, unsigned short* l) {
    __builtin_amdgcn_global_load_lds((const __attribute__((address_space(1))) void*)g,
                                     (__attribute__((address_space(3))) void*)l, 16, 0, 0);
}

__global__ void cvt_f32_bf16(const float* __restrict__ in,
                             unsigned short* __restrict__ out, int n4) {
    int i = blockIdx.x * blockDim.x + threadIdx.x;
    if (i >= n4) return;
    float4 v = reinterpret_cast<const float4*>(in)[i];
    ushort4 o;
    o.x = f2bf(v.x); o.y = f2bf(v.y); o.z = f2bf(v.z); o.w = f2bf(v.w);
    reinterpret_cast<ushort4*>(out)[i] = o;
}

// all 4 weights in one dispatch; dst buffers are contiguous (wq|wk|wv|wo)
__global__ void cvt_weights(const float* __restrict__ Wq, const float* __restrict__ Wk,
                            const float* __restrict__ Wv, const float* __restrict__ Wo,
                            unsigned short* __restrict__ dst) {
    int i = blockIdx.x * blockDim.x + threadIdx.x;   // 0..1048575 float4-groups
    int which = i >> 18;                              // 262144 groups per weight
    const float* src = which == 0 ? Wq : which == 1 ? Wk : which == 2 ? Wv : Wo;
    float4 v = reinterpret_cast<const float4*>(src)[i & 262143];
    ushort4 o;
    o.x = f2bf(v.x); o.y = f2bf(v.y); o.z = f2bf(v.z); o.w = f2bf(v.w);
    reinterpret_cast<ushort4*>(dst)[i] = o;
}

// ---------------- fused QKV projection ------------------------------------
// grid (24, 64): blockIdx.x>>3 selects {Q,K,V}; double-buffered DMA staging.
// mode 0: Q (RoPE + scale log2e/8), 1: K (RoPE), 2: V. Store dense [bh][l][d].
__global__ __launch_bounds__(256) void proj_qkv(
    const unsigned short* __restrict__ X,
    const unsigned short* __restrict__ Wq_,
    const unsigned short* __restrict__ Wk_,
    const unsigned short* __restrict__ Wv_,
    const float* __restrict__ bq_,
    const float* __restrict__ bk_,
    const float* __restrict__ bv_,
    unsigned short* __restrict__ Qb,
    unsigned short* __restrict__ Kb,
    unsigned short* __restrict__ Vr)
{
    __shared__ unsigned short a_lds[2][128 * LDA];
    __shared__ unsigned short b_lds[2][128 * LDA];
    const int tid  = threadIdx.x;
    const int lane = tid & 63;
    const int w    = tid >> 6;
    const int wm   = w & 1, wn = w >> 1;
    const int quad = lane >> 4, l16 = lane & 15;

    const int sel = blockIdx.x >> 3;      // 0=Q 1=K 2=V
    const unsigned short* W = sel == 0 ? Wq_ : (sel == 1 ? Wk_ : Wv_);
    const float* bias       = sel == 0 ? bq_ : (sel == 1 ? bk_ : bv_);
    unsigned short* out     = sel == 0 ? Qb  : (sel == 1 ? Kb  : Vr);
    const int n0 = (blockIdx.x & 7) * 128;
    const int m0 = blockIdx.y * 128;

    f32x4 acc[4][4];
#pragma unroll
    for (int i = 0; i < 4; ++i)
#pragma unroll
        for (int j = 0; j < 4; ++j) acc[i][j] = (f32x4){0.f, 0.f, 0.f, 0.f};

    const int drow = lane >> 2;            // 0..15
    const int dcol = (lane & 3) << 3;      // shorts

    // prologue: stage tile 0 into buffer 0
#pragma unroll
    for (int t = 0; t < 2; ++t) {
        int r0 = w * 32 + t * 16;
        dma16(X + (size_t)(m0 + r0 + drow) * DMODEL + dcol, &a_lds[0][r0 * LDA]);
        dma16(W + (size_t)(n0 + r0 + drow) * DMODEL + dcol, &b_lds[0][r0 * LDA]);
    }

    for (int it = 0; it < 32; ++it) {
        __syncthreads();   // drains vmcnt: buf[it&1] DMA complete; prior readers done
        int cb = it & 1;
        if (it < 31) {     // prefetch next tile into other buffer (lands during MFMA)
            int kk = (it + 1) * 32;
#pragma unroll
            for (int t = 0; t < 2; ++t) {
                int r0 = w * 32 + t * 16;
                dma16(X + (size_t)(m0 + r0 + drow) * DMODEL + kk + dcol, &a_lds[cb ^ 1][r0 * LDA]);
                dma16(W + (size_t)(n0 + r0 + drow) * DMODEL + kk + dcol, &b_lds[cb ^ 1][r0 * LDA]);
            }
        }
        short8 af[4], bf[4];
#pragma unroll
        for (int mt = 0; mt < 4; ++mt)
            af[mt] = *reinterpret_cast<const short8*>(&a_lds[cb][(wm * 64 + mt * 16 + l16) * LDA + quad * 8]);
#pragma unroll
        for (int nt = 0; nt < 4; ++nt)
            bf[nt] = *reinterpret_cast<const short8*>(&b_lds[cb][(wn * 64 + nt * 16 + l16) * LDA + quad * 8]);
#pragma unroll
        for (int mt = 0; mt < 4; ++mt)
#pragma unroll
            for (int nt = 0; nt < 4; ++nt)
                acc[mt][nt] = __builtin_amdgcn_mfma_f32_16x16x32_bf16(af[mt], bf[nt], acc[mt][nt], 0, 0, 0);
    }

    // epilogue: bias (+ RoPE for Q/K); dense [bh][l][d] store
#pragma unroll
    for (int nt = 0; nt < 4; ++nt) {
        int n_g = n0 + wn * 64 + nt * 16 + l16;
        float bv = bias[n_g];
        int d  = n_g & (HEADD - 1);
        int h  = n_g >> 6;
        float sgn = (d & 1) ? 1.0f : -1.0f;
        int i2 = d >> 1;
        float inv_f = expf(-0.28782313662425574f * (float)i2);  // 10000^(-i2/32)
#pragma unroll
        for (int mt = 0; mt < 4; ++mt) {
#pragma unroll
            for (int r = 0; r < 4; ++r) {
                int m_g = m0 + wm * 64 + mt * 16 + quad * 4 + r;
                float v = acc[mt][nt][r] + bv;
                int b    = m_g >> 11;
                int lpos = m_g & (L_SEQ - 1);
                if (sel < 2) {
                    float p = __shfl_xor(v, 1);   // partner (d^1), same row
                    float ang = (float)lpos * inv_f;
                    float cv = cosf(ang), sv = sinf(ang);
                    v = v * cv + sgn * sv * p;
                    if (sel == 0) v *= 0.18033688011112042f;  // log2e/8
                }
                out[((size_t)(b * NHEAD + h) * L_SEQ + lpos) * HEADD + d] = f2bf(v);
            }
        }
    }
}

// ---------------- V transpose: [bh][l][d] -> [bh][d][l] ---------------------
__global__ __launch_bounds__(256) void transpose_v(
    const unsigned short* __restrict__ Vr, unsigned short* __restrict__ Vt)
{
    __shared__ unsigned short tile[64 * 72];
    const int tid = threadIdx.x;
    const int bh  = blockIdx.y;
    const int l0  = blockIdx.x * 64;
#pragma unroll
    for (int t = 0; t < 2; ++t) {
        int c = tid + t * 256;
        int row = c >> 3, cc = (c & 7) << 3;
        int4 v = *reinterpret_cast<const int4*>(Vr + ((size_t)bh * L_SEQ + l0 + row) * HEADD + cc);
        *reinterpret_cast<int4*>(&tile[row * 72 + cc]) = v;
    }
    __syncthreads();
#pragma unroll
    for (int t = 0; t < 2; ++t) {
        int c = tid + t * 256;
        int d = c >> 3, lc = (c & 7) << 3;
        union { unsigned short u[8]; int4 v; } tt;
#pragma unroll
        for (int j = 0; j < 8; ++j) tt.u[j] = tile[(lc + j) * 72 + d];
        *reinterpret_cast<int4*>(Vt + ((size_t)bh * HEADD + d) * L_SEQ + l0 + lc) = tt.v;
    }
}

// ---------------- flash attention (causal), S^T formulation -----------------
#define LDK 88

__global__ __launch_bounds__(256) void attn_fwd(
    const unsigned short* __restrict__ Q,
    const unsigned short* __restrict__ K,
    const unsigned short* __restrict__ Vt,
    unsigned short* __restrict__ Oa)
{
    __shared__ unsigned short k_lds[64 * LDK];
    __shared__ unsigned short v_lds[64 * LDK];
    const int tid  = threadIdx.x;
    const int lane = tid & 63;
    const int w    = tid >> 6;
    const int quad = lane >> 4, l16 = lane & 15;
    const int pair = blockIdx.x;
    const int bh   = blockIdx.y;
    const size_t base = (size_t)bh * L_SEQ * HEADD;

    const int srow0 = tid >> 3;
    const int scc   = (tid & 7) << 3;
    const int b = bh >> 4, h = bh & 15;

    for (int half = 0; half < 2; ++half) {
        const int qb = half ? (31 - pair) : pair;
        const int qrow = qb * 64 + w * 16 + l16;

        short8 qf[2];
#pragma unroll
        for (int ks = 0; ks < 2; ++ks)
            qf[ks] = *reinterpret_cast<const short8*>(Q + base + (size_t)qrow * HEADD + ks * 32 + quad * 8);

        f32x4 o[4];
#pragma unroll
        for (int nt = 0; nt < 4; ++nt) o[nt] = (f32x4){0.f, 0.f, 0.f, 0.f};
        float lsum = 0.f;

        int4 ka0 = *reinterpret_cast<const int4*>(K  + base + (size_t)srow0 * HEADD + scc);
        int4 ka1 = *reinterpret_cast<const int4*>(K  + base + (size_t)(srow0 + 32) * HEADD + scc);
        int4 va0 = *reinterpret_cast<const int4*>(Vt + base + (size_t)srow0 * L_SEQ + scc);
        int4 va1 = *reinterpret_cast<const int4*>(Vt + base + (size_t)(srow0 + 32) * L_SEQ + scc);

        for (int kb = 0; kb <= qb; ++kb) {
            __syncthreads();
            *reinterpret_cast<int4*>(&k_lds[srow0 * LDK + scc])        = ka0;
            *reinterpret_cast<int4*>(&k_lds[(srow0 + 32) * LDK + scc]) = ka1;
            *reinterpret_cast<int4*>(&v_lds[srow0 * LDK + scc])        = va0;
            *reinterpret_cast<int4*>(&v_lds[(srow0 + 32) * LDK + scc]) = va1;
            __syncthreads();

            if (kb < qb) {
                int kn = kb + 1;
                ka0 = *reinterpret_cast<const int4*>(K  + base + (size_t)(kn * 64 + srow0) * HEADD + scc);
                ka1 = *reinterpret_cast<const int4*>(K  + base + (size_t)(kn * 64 + srow0 + 32) * HEADD + scc);
                va0 = *reinterpret_cast<const int4*>(Vt + base + (size_t)srow0 * L_SEQ + kn * 64 + scc);
                va1 = *reinterpret_cast<const int4*>(Vt + base + (size_t)(srow0 + 32) * L_SEQ + kn * 64 + scc);
            }

            f32x4 st[4];
#pragma unroll
            for (int nt = 0; nt < 4; ++nt) st[nt] = (f32x4){0.f, 0.f, 0.f, 0.f};
#pragma unroll
            for (int ks = 0; ks < 2; ++ks)
#pragma unroll
                for (int nt = 0; nt < 4; ++nt) {
                    short8 kf = *reinterpret_cast<const short8*>(&k_lds[(nt * 16 + l16) * LDK + ks * 32 + quad * 8]);
                    st[nt] = __builtin_amdgcn_mfma_f32_16x16x32_bf16(kf, qf[ks], st[nt], 0, 0, 0);
                }

            if (kb == qb) {
#pragma unroll
                for (int nt = 0; nt < 4; ++nt)
#pragma unroll
                    for (int r = 0; r < 4; ++r) {
                        int seqcol = kb * 64 + nt * 16 + quad * 4 + r;
                        if (seqcol > qrow) st[nt][r] = -INFINITY;
                    }
            }

            short4v pfrag[4];
#pragma unroll
            for (int nt = 0; nt < 4; ++nt) {
                float p0 = __builtin_amdgcn_exp2f(st[nt][0]);
                float p1 = __builtin_amdgcn_exp2f(st[nt][1]);
                float p2 = __builtin_amdgcn_exp2f(st[nt][2]);
                float p3 = __builtin_amdgcn_exp2f(st[nt][3]);
                lsum += (p0 + p1) + (p2 + p3);
                unsigned u0 = __float_as_uint(p0) + 0x8000u;
                unsigned u1 = __float_as_uint(p1) + 0x8000u;
                unsigned u2 = __float_as_uint(p2) + 0x8000u;
                unsigned u3 = __float_as_uint(p3) + 0x8000u;
                union { unsigned u[2]; short4v v; } pk;
                pk.u[0] = (u0 >> 16) | (u1 & 0xffff0000u);
                pk.u[1] = (u2 >> 16) | (u3 & 0xffff0000u);
                pfrag[nt] = pk.v;
            }

#pragma unroll
            for (int c = 0; c < 4; ++c)
#pragma unroll
                for (int nt2 = 0; nt2 < 4; ++nt2) {
                    short4v vf = *reinterpret_cast<const short4v*>(
                        &v_lds[(nt2 * 16 + l16) * LDK + c * 16 + quad * 4]);
                    o[nt2] = __builtin_amdgcn_mfma_f32_16x16x16bf16_1k(pfrag[c], vf, o[nt2], 0, 0, 0);
                }
        }

        lsum += __shfl_xor(lsum, 16);
        lsum += __shfl_xor(lsum, 32);
        float rs[4];
#pragma unroll
        for (int r = 0; r < 4; ++r) rs[r] = __shfl(lsum, quad * 4 + r);
#pragma unroll
        for (int r = 0; r < 4; ++r) {
            float inv = 1.0f / rs[r];
            int lg = qb * 64 + w * 16 + quad * 4 + r;
#pragma unroll
            for (int nt = 0; nt < 4; ++nt) {
                int d = nt * 16 + l16;
                Oa[(size_t)(b * L_SEQ + lg) * DMODEL + h * HEADD + d] = f2bf(o[nt][r] * inv);
            }
        }
    }
}

// ---------------- output projection: fp32 out = A @ Wo^T + bo ---------------
__global__ __launch_bounds__(256) void out_gemm(
    const unsigned short* __restrict__ X,
    const unsigned short* __restrict__ W,
    const float* __restrict__ bias,
    float* __restrict__ out)
{
    __shared__ unsigned short a_lds[2][128 * LDA];
    __shared__ unsigned short b_lds[2][128 * LDA];
    const int tid  = threadIdx.x;
    const int lane = tid & 63;
    const int w    = tid >> 6;
    const int wm   = w & 1, wn = w >> 1;
    const int quad = lane >> 4, l16 = lane & 15;
    const int m0 = blockIdx.y * 128;
    const int n0 = blockIdx.x * 128;

    f32x4 acc[4][4];
#pragma unroll
    for (int i = 0; i < 4; ++i)
#pragma unroll
        for (int j = 0; j < 4; ++j) acc[i][j] = (f32x4){0.f, 0.f, 0.f, 0.f};

    const int drow = lane >> 2;
    const int dcol = (lane & 3) << 3;

#pragma unroll
    for (int t = 0; t < 2; ++t) {
        int r0 = w * 32 + t * 16;
        dma16(X + (size_t)(m0 + r0 + drow) * DMODEL + dcol, &a_lds[0][r0 * LDA]);
        dma16(W + (size_t)(n0 + r0 + drow) * DMODEL + dcol, &b_lds[0][r0 * LDA]);
    }

    for (int it = 0; it < 32; ++it) {
        __syncthreads();
        int cb = it & 1;
        if (it < 31) {
            int kk = (it + 1) * 32;
#pragma unroll
            for (int t = 0; t < 2; ++t) {
                int r0 = w * 32 + t * 16;
                dma16(X + (size_t)(m0 + r0 + drow) * DMODEL + kk + dcol, &a_lds[cb ^ 1][r0 * LDA]);
                dma16(W + (size_t)(n0 + r0 + drow) * DMODEL + kk + dcol, &b_lds[cb ^ 1][r0 * LDA]);
            }
        }
        short8 af[4], bf[4];
#pragma unroll
        for (int mt = 0; mt < 4; ++mt)
            af[mt] = *reinterpret_cast<const short8*>(&a_lds[cb][(wm * 64 + mt * 16 + l16) * LDA + quad * 8]);
#pragma unroll
        for (int nt = 0; nt < 4; ++nt)
            bf[nt] = *reinterpret_cast<const short8*>(&b_lds[cb][(wn * 64 + nt * 16 + l16) * LDA + quad * 8]);
#pragma unroll
        for (int mt = 0; mt < 4; ++mt)
#pragma unroll
            for (int nt = 0; nt < 4; ++nt)
                acc[mt][nt] = __builtin_amdgcn_mfma_f32_16x16x32_bf16(af[mt], bf[nt], acc[mt][nt], 0, 0, 0);
    }

#pragma unroll
    for (int nt = 0; nt < 4; ++nt) {
        int n_g = n0 + wn * 64 + nt * 16 + l16;
        float bv = bias[n_g];
#pragma unroll
        for (int mt = 0; mt < 4; ++mt)
#pragma unroll
            for (int r = 0; r < 4; ++r) {
                int m_g = m0 + wm * 64 + mt * 16 + quad * 4 + r;
                out[(size_t)m_g * DMODEL + n_g] = acc[mt][nt][r] + bv;
            }
    }
}

extern "C" void kernel_launch(void* const* d_in, const int* in_sizes, int n_in,
                              void* d_out, int out_size, void* d_ws, size_t ws_size,
                              hipStream_t stream) {
    const float* query = (const float*)d_in[0];
    const float* Wq = (const float*)d_in[1];
    const float* bq = (const float*)d_in[2];
    const float* Wk = (const float*)d_in[3];
    const float* bk = (const float*)d_in[4];
    const float* Wv = (const float*)d_in[5];
    const float* bv = (const float*)d_in[6];
    const float* Wo = (const float*)d_in[7];
    const float* bo = (const float*)d_in[8];
    float* out = (float*)d_out;

    unsigned short* ws  = (unsigned short*)d_ws;
    unsigned short* xb  = ws;                       // 8192*1024
    unsigned short* wqb = xb  + (size_t)8388608;    // 1024*1024 each, CONTIGUOUS
    unsigned short* wkb = wqb + 1048576;
    unsigned short* wvb = wkb + 1048576;
    unsigned short* wob = wvb + 1048576;
    unsigned short* Qb  = wob + 1048576;            // [bh][l][d]
    unsigned short* Kb  = Qb  + 8388608;
    unsigned short* Vr  = Kb  + 8388608;            // [bh][l][d]
    unsigned short* Vtb = Vr  + 8388608;            // [bh][d][l]
    unsigned short* Ab  = Vtb + 8388608;            // [b][l][h*d]

    cvt_f32_bf16<<<8192, 256, 0, stream>>>(query, xb, 2097152);
    cvt_weights<<<4096, 256, 0, stream>>>(Wq, Wk, Wv, Wo, wqb);

    proj_qkv<<<dim3(24, 64), 256, 0, stream>>>(xb, wqb, wkb, wvb, bq, bk, bv, Qb, Kb, Vr);
    transpose_v<<<dim3(32, 64), 256, 0, stream>>>(Vr, Vtb);
    attn_fwd<<<dim3(16, 64), 256, 0, stream>>>(Qb, Kb, Vtb, Ab);
    out_gemm<<<dim3(8, 64), 256, 0, stream>>>(Ab, wob, bo, out);
}

// Round 8
// 329.858 us; speedup vs baseline: 2.4119x; 1.2060x over previous
//
#include <hip/hip_runtime.h>
#include <hip/hip_bf16.h>
#include <math.h>

#define L_SEQ  2048
#define DMODEL 1024
#define NHEAD  16
#define HEADD  64

typedef __attribute__((ext_vector_type(8))) short short8;
typedef __attribute__((ext_vector_type(4))) short short4v;
typedef __attribute__((ext_vector_type(4))) float f32x4;

#define LDA 32   // unpadded: global_load_lds writes lane*16B contiguous

// RNE float -> bf16 bits
static __device__ __forceinline__ unsigned short f2bf(float f) {
    unsigned int u = __float_as_uint(f);
    unsigned int r = (u + 0x7fffu + ((u >> 16) & 1u)) >> 16;
    return (unsigned short)r;
}

static __device__ __forceinline__ void dma16(const unsigned short* g, unsigned short* l) {
    __builtin_amdgcn_global_load_lds((const __attribute__((address_space(1))) void*)g,
                                     (__attribute__((address_space(3))) void*)l, 16, 0, 0);
}

__global__ void cvt_f32_bf16(const float* __restrict__ in,
                             unsigned short* __restrict__ out, int n4) {
    int i = blockIdx.x * blockDim.x + threadIdx.x;
    if (i >= n4) return;
    float4 v = reinterpret_cast<const float4*>(in)[i];
    ushort4 o;
    o.x = f2bf(v.x); o.y = f2bf(v.y); o.z = f2bf(v.z); o.w = f2bf(v.w);
    reinterpret_cast<ushort4*>(out)[i] = o;
}

// all 4 weights in one dispatch; dst buffers are contiguous (wq|wk|wv|wo)
__global__ void cvt_weights(const float* __restrict__ Wq, const float* __restrict__ Wk,
                            const float* __restrict__ Wv, const float* __restrict__ Wo,
                            unsigned short* __restrict__ dst) {
    int i = blockIdx.x * blockDim.x + threadIdx.x;   // 0..1048575 float4-groups
    int which = i >> 18;                              // 262144 groups per weight
    const float* src = which == 0 ? Wq : which == 1 ? Wk : which == 2 ? Wv : Wo;
    float4 v = reinterpret_cast<const float4*>(src)[i & 262143];
    ushort4 o;
    o.x = f2bf(v.x); o.y = f2bf(v.y); o.z = f2bf(v.z); o.w = f2bf(v.w);
    reinterpret_cast<ushort4*>(dst)[i] = o;
}

// RoPE table: tab[lpos*32+i2] = (cos, sin) of lpos * 10000^(-i2/32).
// Same cosf/sinf math as the old in-epilogue code -> bit-identical output,
// but computed 65536 times total instead of ~21M times (round 7: cosf/sinf
// per output element = 40% VALUBusy in proj_qkv).
__global__ void build_rope(float* __restrict__ tab) {
    int i = blockIdx.x * blockDim.x + threadIdx.x;   // 0..65535
    int lpos = i >> 5, i2 = i & 31;
    float inv_f = expf(-0.28782313662425574f * (float)i2);  // 10000^(-i2/32)
    float ang = (float)lpos * inv_f;
    tab[2 * i]     = cosf(ang);
    tab[2 * i + 1] = sinf(ang);
}

// ---------------- fused QKV projection ------------------------------------
// grid (24, 64): blockIdx.x>>3 selects {Q,K,V}; double-buffered DMA staging.
// sel 0: Q (RoPE + scale log2e/8), 1: K (RoPE), 2: V. Store dense [bh][l][d].
__global__ __launch_bounds__(256) void proj_qkv(
    const unsigned short* __restrict__ X,
    const unsigned short* __restrict__ Wq_,
    const unsigned short* __restrict__ Wk_,
    const unsigned short* __restrict__ Wv_,
    const float* __restrict__ bq_,
    const float* __restrict__ bk_,
    const float* __restrict__ bv_,
    const float* __restrict__ rope,
    unsigned short* __restrict__ Qb,
    unsigned short* __restrict__ Kb,
    unsigned short* __restrict__ Vr)
{
    __shared__ unsigned short a_lds[2][128 * LDA];
    __shared__ unsigned short b_lds[2][128 * LDA];
    const int tid  = threadIdx.x;
    const int lane = tid & 63;
    const int w    = tid >> 6;
    const int wm   = w & 1, wn = w >> 1;
    const int quad = lane >> 4, l16 = lane & 15;

    const int sel = blockIdx.x >> 3;      // 0=Q 1=K 2=V
    const unsigned short* W = sel == 0 ? Wq_ : (sel == 1 ? Wk_ : Wv_);
    const float* bias       = sel == 0 ? bq_ : (sel == 1 ? bk_ : bv_);
    unsigned short* out     = sel == 0 ? Qb  : (sel == 1 ? Kb  : Vr);
    const int n0 = (blockIdx.x & 7) * 128;
    const int m0 = blockIdx.y * 128;

    f32x4 acc[4][4];
#pragma unroll
    for (int i = 0; i < 4; ++i)
#pragma unroll
        for (int j = 0; j < 4; ++j) acc[i][j] = (f32x4){0.f, 0.f, 0.f, 0.f};

    const int drow = lane >> 2;            // 0..15
    const int dcol = (lane & 3) << 3;      // shorts

    // prologue: stage tile 0 into buffer 0
#pragma unroll
    for (int t = 0; t < 2; ++t) {
        int r0 = w * 32 + t * 16;
        dma16(X + (size_t)(m0 + r0 + drow) * DMODEL + dcol, &a_lds[0][r0 * LDA]);
        dma16(W + (size_t)(n0 + r0 + drow) * DMODEL + dcol, &b_lds[0][r0 * LDA]);
    }

    for (int it = 0; it < 32; ++it) {
        __syncthreads();   // drains vmcnt: buf[it&1] DMA complete; prior readers done
        int cb = it & 1;
        if (it < 31) {     // prefetch next tile into other buffer (lands during MFMA)
            int kk = (it + 1) * 32;
#pragma unroll
            for (int t = 0; t < 2; ++t) {
                int r0 = w * 32 + t * 16;
                dma16(X + (size_t)(m0 + r0 + drow) * DMODEL + kk + dcol, &a_lds[cb ^ 1][r0 * LDA]);
                dma16(W + (size_t)(n0 + r0 + drow) * DMODEL + kk + dcol, &b_lds[cb ^ 1][r0 * LDA]);
            }
        }
        short8 af[4], bf[4];
#pragma unroll
        for (int mt = 0; mt < 4; ++mt)
            af[mt] = *reinterpret_cast<const short8*>(&a_lds[cb][(wm * 64 + mt * 16 + l16) * LDA + quad * 8]);
#pragma unroll
        for (int nt = 0; nt < 4; ++nt)
            bf[nt] = *reinterpret_cast<const short8*>(&b_lds[cb][(wn * 64 + nt * 16 + l16) * LDA + quad * 8]);
#pragma unroll
        for (int mt = 0; mt < 4; ++mt)
#pragma unroll
            for (int nt = 0; nt < 4; ++nt)
                acc[mt][nt] = __builtin_amdgcn_mfma_f32_16x16x32_bf16(af[mt], bf[nt], acc[mt][nt], 0, 0, 0);
    }

    // epilogue: bias (+ RoPE via table for Q/K); dense [bh][l][d] store
#pragma unroll
    for (int nt = 0; nt < 4; ++nt) {
        int n_g = n0 + wn * 64 + nt * 16 + l16;
        float bv = bias[n_g];
        int d  = n_g & (HEADD - 1);
        int h  = n_g >> 6;
        float sgn = (d & 1) ? 1.0f : -1.0f;
        int i2 = d >> 1;
#pragma unroll
        for (int mt = 0; mt < 4; ++mt) {
#pragma unroll
            for (int r = 0; r < 4; ++r) {
                int m_g = m0 + wm * 64 + mt * 16 + quad * 4 + r;
                float v = acc[mt][nt][r] + bv;
                int b    = m_g >> 11;
                int lpos = m_g & (L_SEQ - 1);
                if (sel < 2) {
                    float p = __shfl_xor(v, 1);   // partner (d^1), same row
                    float2 cs = *reinterpret_cast<const float2*>(&rope[(size_t)(lpos * 32 + i2) * 2]);
                    v = v * cs.x + sgn * cs.y * p;
                    if (sel == 0) v *= 0.18033688011112042f;  // log2e/8
                }
                out[((size_t)(b * NHEAD + h) * L_SEQ + lpos) * HEADD + d] = f2bf(v);
            }
        }
    }
}

// ---------------- V transpose: [bh][l][d] -> [bh][d][l] ---------------------
__global__ __launch_bounds__(256) void transpose_v(
    const unsigned short* __restrict__ Vr, unsigned short* __restrict__ Vt)
{
    __shared__ unsigned short tile[64 * 72];
    const int tid = threadIdx.x;
    const int bh  = blockIdx.y;
    const int l0  = blockIdx.x * 64;
#pragma unroll
    for (int t = 0; t < 2; ++t) {
        int c = tid + t * 256;
        int row = c >> 3, cc = (c & 7) << 3;
        int4 v = *reinterpret_cast<const int4*>(Vr + ((size_t)bh * L_SEQ + l0 + row) * HEADD + cc);
        *reinterpret_cast<int4*>(&tile[row * 72 + cc]) = v;
    }
    __syncthreads();
#pragma unroll
    for (int t = 0; t < 2; ++t) {
        int c = tid + t * 256;
        int d = c >> 3, lc = (c & 7) << 3;
        union { unsigned short u[8]; int4 v; } tt;
#pragma unroll
        for (int j = 0; j < 8; ++j) tt.u[j] = tile[(lc + j) * 72 + d];
        *reinterpret_cast<int4*>(Vt + ((size_t)bh * HEADD + d) * L_SEQ + l0 + lc) = tt.v;
    }
}

// ---------------- flash attention (causal), S^T formulation -----------------
#define LDK 88

__global__ __launch_bounds__(256) void attn_fwd(
    const unsigned short* __restrict__ Q,
    const unsigned short* __restrict__ K,
    const unsigned short* __restrict__ Vt,
    unsigned short* __restrict__ Oa)
{
    __shared__ unsigned short k_lds[64 * LDK];
    __shared__ unsigned short v_lds[64 * LDK];
    const int tid  = threadIdx.x;
    const int lane = tid & 63;
    const int w    = tid >> 6;
    const int quad = lane >> 4, l16 = lane & 15;
    const int pair = blockIdx.x;
    const int bh   = blockIdx.y;
    const size_t base = (size_t)bh * L_SEQ * HEADD;

    const int srow0 = tid >> 3;
    const int scc   = (tid & 7) << 3;
    const int b = bh >> 4, h = bh & 15;

    for (int half = 0; half < 2; ++half) {
        const int qb = half ? (31 - pair) : pair;
        const int qrow = qb * 64 + w * 16 + l16;

        short8 qf[2];
#pragma unroll
        for (int ks = 0; ks < 2; ++ks)
            qf[ks] = *reinterpret_cast<const short8*>(Q + base + (size_t)qrow * HEADD + ks * 32 + quad * 8);

        f32x4 o[4];
#pragma unroll
        for (int nt = 0; nt < 4; ++nt) o[nt] = (f32x4){0.f, 0.f, 0.f, 0.f};
        float lsum = 0.f;

        int4 ka0 = *reinterpret_cast<const int4*>(K  + base + (size_t)srow0 * HEADD + scc);
        int4 ka1 = *reinterpret_cast<const int4*>(K  + base + (size_t)(srow0 + 32) * HEADD + scc);
        int4 va0 = *reinterpret_cast<const int4*>(Vt + base + (size_t)srow0 * L_SEQ + scc);
        int4 va1 = *reinterpret_cast<const int4*>(Vt + base + (size_t)(srow0 + 32) * L_SEQ + scc);

        for (int kb = 0; kb <= qb; ++kb) {
            __syncthreads();
            *reinterpret_cast<int4*>(&k_lds[srow0 * LDK + scc])        = ka0;
            *reinterpret_cast<int4*>(&k_lds[(srow0 + 32) * LDK + scc]) = ka1;
            *reinterpret_cast<int4*>(&v_lds[srow0 * LDK + scc])        = va0;
            *reinterpret_cast<int4*>(&v_lds[(srow0 + 32) * LDK + scc]) = va1;
            __syncthreads();

            if (kb < qb) {
                int kn = kb + 1;
                ka0 = *reinterpret_cast<const int4*>(K  + base + (size_t)(kn * 64 + srow0) * HEADD + scc);
                ka1 = *reinterpret_cast<const int4*>(K  + base + (size_t)(kn * 64 + srow0 + 32) * HEADD + scc);
                va0 = *reinterpret_cast<const int4*>(Vt + base + (size_t)srow0 * L_SEQ + kn * 64 + scc);
                va1 = *reinterpret_cast<const int4*>(Vt + base + (size_t)(srow0 + 32) * L_SEQ + kn * 64 + scc);
            }

            f32x4 st[4];
#pragma unroll
            for (int nt = 0; nt < 4; ++nt) st[nt] = (f32x4){0.f, 0.f, 0.f, 0.f};
#pragma unroll
            for (int ks = 0; ks < 2; ++ks)
#pragma unroll
                for (int nt = 0; nt < 4; ++nt) {
                    short8 kf = *reinterpret_cast<const short8*>(&k_lds[(nt * 16 + l16) * LDK + ks * 32 + quad * 8]);
                    st[nt] = __builtin_amdgcn_mfma_f32_16x16x32_bf16(kf, qf[ks], st[nt], 0, 0, 0);
                }

            if (kb == qb) {
#pragma unroll
                for (int nt = 0; nt < 4; ++nt)
#pragma unroll
                    for (int r = 0; r < 4; ++r) {
                        int seqcol = kb * 64 + nt * 16 + quad * 4 + r;
                        if (seqcol > qrow) st[nt][r] = -INFINITY;
                    }
            }

            short4v pfrag[4];
#pragma unroll
            for (int nt = 0; nt < 4; ++nt) {
                float p0 = __builtin_amdgcn_exp2f(st[nt][0]);
                float p1 = __builtin_amdgcn_exp2f(st[nt][1]);
                float p2 = __builtin_amdgcn_exp2f(st[nt][2]);
                float p3 = __builtin_amdgcn_exp2f(st[nt][3]);
                lsum += (p0 + p1) + (p2 + p3);
                unsigned u0 = __float_as_uint(p0) + 0x8000u;
                unsigned u1 = __float_as_uint(p1) + 0x8000u;
                unsigned u2 = __float_as_uint(p2) + 0x8000u;
                unsigned u3 = __float_as_uint(p3) + 0x8000u;
                union { unsigned u[2]; short4v v; } pk;
                pk.u[0] = (u0 >> 16) | (u1 & 0xffff0000u);
                pk.u[1] = (u2 >> 16) | (u3 & 0xffff0000u);
                pfrag[nt] = pk.v;
            }

#pragma unroll
            for (int c = 0; c < 4; ++c)
#pragma unroll
                for (int nt2 = 0; nt2 < 4; ++nt2) {
                    short4v vf = *reinterpret_cast<const short4v*>(
                        &v_lds[(nt2 * 16 + l16) * LDK + c * 16 + quad * 4]);
                    o[nt2] = __builtin_amdgcn_mfma_f32_16x16x16bf16_1k(pfrag[c], vf, o[nt2], 0, 0, 0);
                }
        }

        lsum += __shfl_xor(lsum, 16);
        lsum += __shfl_xor(lsum, 32);
        float rs[4];
#pragma unroll
        for (int r = 0; r < 4; ++r) rs[r] = __shfl(lsum, quad * 4 + r);
#pragma unroll
        for (int r = 0; r < 4; ++r) {
            float inv = 1.0f / rs[r];
            int lg = qb * 64 + w * 16 + quad * 4 + r;
#pragma unroll
            for (int nt = 0; nt < 4; ++nt) {
                int d = nt * 16 + l16;
                Oa[(size_t)(b * L_SEQ + lg) * DMODEL + h * HEADD + d] = f2bf(o[nt][r] * inv);
            }
        }
    }
}

// ---------------- output projection: fp32 out = A @ Wo^T + bo ---------------
__global__ __launch_bounds__(256) void out_gemm(
    const unsigned short* __restrict__ X,
    const unsigned short* __restrict__ W,
    const float* __restrict__ bias,
    float* __restrict__ out)
{
    __shared__ unsigned short a_lds[2][128 * LDA];
    __shared__ unsigned short b_lds[2][128 * LDA];
    const int tid  = threadIdx.x;
    const int lane = tid & 63;
    const int w    = tid >> 6;
    const int wm   = w & 1, wn = w >> 1;
    const int quad = lane >> 4, l16 = lane & 15;
    const int m0 = blockIdx.y * 128;
    const int n0 = blockIdx.x * 128;

    f32x4 acc[4][4];
#pragma unroll
    for (int i = 0; i < 4; ++i)
#pragma unroll
        for (int j = 0; j < 4; ++j) acc[i][j] = (f32x4){0.f, 0.f, 0.f, 0.f};

    const int drow = lane >> 2;
    const int dcol = (lane & 3) << 3;

#pragma unroll
    for (int t = 0; t < 2; ++t) {
        int r0 = w * 32 + t * 16;
        dma16(X + (size_t)(m0 + r0 + drow) * DMODEL + dcol, &a_lds[0][r0 * LDA]);
        dma16(W + (size_t)(n0 + r0 + drow) * DMODEL + dcol, &b_lds[0][r0 * LDA]);
    }

    for (int it = 0; it < 32; ++it) {
        __syncthreads();
        int cb = it & 1;
        if (it < 31) {
            int kk = (it + 1) * 32;
#pragma unroll
            for (int t = 0; t < 2; ++t) {
                int r0 = w * 32 + t * 16;
                dma16(X + (size_t)(m0 + r0 + drow) * DMODEL + kk + dcol, &a_lds[cb ^ 1][r0 * LDA]);
                dma16(W + (size_t)(n0 + r0 + drow) * DMODEL + kk + dcol, &b_lds[cb ^ 1][r0 * LDA]);
            }
        }
        short8 af[4], bf[4];
#pragma unroll
        for (int mt = 0; mt < 4; ++mt)
            af[mt] = *reinterpret_cast<const short8*>(&a_lds[cb][(wm * 64 + mt * 16 + l16) * LDA + quad * 8]);
#pragma unroll
        for (int nt = 0; nt < 4; ++nt)
            bf[nt] = *reinterpret_cast<const short8*>(&b_lds[cb][(wn * 64 + nt * 16 + l16) * LDA + quad * 8]);
#pragma unroll
        for (int mt = 0; mt < 4; ++mt)
#pragma unroll
            for (int nt = 0; nt < 4; ++nt)
                acc[mt][nt] = __builtin_amdgcn_mfma_f32_16x16x32_bf16(af[mt], bf[nt], acc[mt][nt], 0, 0, 0);
    }

#pragma unroll
    for (int nt = 0; nt < 4; ++nt) {
        int n_g = n0 + wn * 64 + nt * 16 + l16;
        float bv = bias[n_g];
#pragma unroll
        for (int mt = 0; mt < 4; ++mt)
#pragma unroll
            for (int r = 0; r < 4; ++r) {
                int m_g = m0 + wm * 64 + mt * 16 + quad * 4 + r;
                out[(size_t)m_g * DMODEL + n_g] = acc[mt][nt][r] + bv;
            }
    }
}

extern "C" void kernel_launch(void* const* d_in, const int* in_sizes, int n_in,
                              void* d_out, int out_size, void* d_ws, size_t ws_size,
                              hipStream_t stream) {
    const float* query = (const float*)d_in[0];
    const float* Wq = (const float*)d_in[1];
    const float* bq = (const float*)d_in[2];
    const float* Wk = (const float*)d_in[3];
    const float* bk = (const float*)d_in[4];
    const float* Wv = (const float*)d_in[5];
    const float* bv = (const float*)d_in[6];
    const float* Wo = (const float*)d_in[7];
    const float* bo = (const float*)d_in[8];
    float* out = (float*)d_out;

    unsigned short* ws  = (unsigned short*)d_ws;
    unsigned short* xb  = ws;                       // 8192*1024
    unsigned short* wqb = xb  + (size_t)8388608;    // 1024*1024 each, CONTIGUOUS
    unsigned short* wkb = wqb + 1048576;
    unsigned short* wvb = wkb + 1048576;
    unsigned short* wob = wvb + 1048576;
    unsigned short* Qb  = wob + 1048576;            // [bh][l][d]
    unsigned short* Kb  = Qb  + 8388608;
    unsigned short* Vr  = Kb  + 8388608;            // [bh][l][d]
    unsigned short* Vtb = Vr  + 8388608;            // [bh][d][l]
    unsigned short* Ab  = Vtb + 8388608;            // [b][l][h*d]
    float* rope = (float*)(Ab + 8388608);           // 2048*32 float2 = 512 KB

    build_rope<<<256, 256, 0, stream>>>(rope);
    cvt_f32_bf16<<<8192, 256, 0, stream>>>(query, xb, 2097152);
    cvt_weights<<<4096, 256, 0, stream>>>(Wq, Wk, Wv, Wo, wqb);

    proj_qkv<<<dim3(24, 64), 256, 0, stream>>>(xb, wqb, wkb, wvb, bq, bk, bv, rope, Qb, Kb, Vr);
    transpose_v<<<dim3(32, 64), 256, 0, stream>>>(Vr, Vtb);
    attn_fwd<<<dim3(16, 64), 256, 0, stream>>>(Qb, Kb, Vtb, Ab);
    out_gemm<<<dim3(8, 64), 256, 0, stream>>>(Ab, wob, bo, out);
}